// Round 2
// baseline (182.590 us; speedup 1.0000x reference)
//
#include <hip/hip_runtime.h>
#include <math.h>

// Problem constants (B=64, J=17, H=W=128)
#define BJ    1088               // B*J map-pairs (pred_m paired with gt_m)
#define HW    16384              // 128*128
#define NTH   512                // 8 waves per block
#define NWAVE (NTH / 64)
#define F4PT  (HW / 4 / NTH)     // 8 float4 per thread per map

// Monotonic unsigned key for float bits: orders like float compare.
__device__ __forceinline__ unsigned int ford(unsigned int u) {
    return (u & 0x80000000u) ? ~u : (u | 0x80000000u);
}
__device__ __forceinline__ unsigned int ford_inv(unsigned int o) {
    return (o & 0x80000000u) ? (o & 0x7fffffffu) : ~o;
}

// Per-thread 4-chain max scan -> u64 key (ord(val)<<32)|~idx.
// max over keys = (max val, min idx): matches argmax-first semantics.
__device__ __forceinline__ unsigned long long max_key(const float4 (&v)[F4PT], int t)
{
    float mx0 = -INFINITY, mx1 = -INFINITY, mx2 = -INFINITY, mx3 = -INFINITY;
    int   ix0 = 0, ix1 = 1, ix2 = 2, ix3 = 3;
#pragma unroll
    for (int k = 0; k < F4PT; ++k) {               // idx grows with k -> '>' keeps first
        const int base = (t + k * NTH) << 2;
        if (v[k].x > mx0) { mx0 = v[k].x; ix0 = base;     }
        if (v[k].y > mx1) { mx1 = v[k].y; ix1 = base + 1; }
        if (v[k].z > mx2) { mx2 = v[k].z; ix2 = base + 2; }
        if (v[k].w > mx3) { mx3 = v[k].w; ix3 = base + 3; }
    }
    unsigned long long k0 = ((unsigned long long)ford(__float_as_uint(mx0)) << 32) | (unsigned int)~ix0;
    unsigned long long k1 = ((unsigned long long)ford(__float_as_uint(mx1)) << 32) | (unsigned int)~ix1;
    unsigned long long k2 = ((unsigned long long)ford(__float_as_uint(mx2)) << 32) | (unsigned int)~ix2;
    unsigned long long k3 = ((unsigned long long)ford(__float_as_uint(mx3)) << 32) | (unsigned int)~ix3;
    unsigned long long key = k0 > k1 ? k0 : k1;
    key = k2 > key ? k2 : key;
    key = k3 > key ? k3 : key;
#pragma unroll
    for (int off = 32; off >= 1; off >>= 1) {
        const unsigned long long ok = __shfl_xor(key, off, 64);
        key = (ok > key) ? ok : key;
    }
    return key;
}

// Masked distance sum over this thread's 32 elements.
__device__ __forceinline__ void masked_sum(const float4 (&v)[F4PT], int t,
                                           float thv, float ym, float xm,
                                           float& s, float& c)
{
#pragma unroll
    for (int k = 0; k < F4PT; ++k) {
        const float4 w = v[k];
        const int g4 = t + k * NTH;
        const float dy  = (float)(g4 >> 5) - ym;   // all 4 elems share a row
        const float dy2 = dy * dy;
        const float cb  = (float)((g4 << 2) & 127) - xm;
        {
            const float dx = cb;        const float ds = __builtin_amdgcn_sqrtf(fmaf(dx, dx, dy2));
            const float mk = (w.x > thv) ? 1.0f : 0.0f;  s = fmaf(mk, ds, s);  c += mk;
        }
        {
            const float dx = cb + 1.0f; const float ds = __builtin_amdgcn_sqrtf(fmaf(dx, dx, dy2));
            const float mk = (w.y > thv) ? 1.0f : 0.0f;  s = fmaf(mk, ds, s);  c += mk;
        }
        {
            const float dx = cb + 2.0f; const float ds = __builtin_amdgcn_sqrtf(fmaf(dx, dx, dy2));
            const float mk = (w.z > thv) ? 1.0f : 0.0f;  s = fmaf(mk, ds, s);  c += mk;
        }
        {
            const float dx = cb + 3.0f; const float ds = __builtin_amdgcn_sqrtf(fmaf(dx, dx, dy2));
            const float mk = (w.w > thv) ? 1.0f : 0.0f;  s = fmaf(mk, ds, s);  c += mk;
        }
    }
}

// R10: pair-fused single kernel. One block handles pred map m AND gt map m
// (128 KB, 16 float4/thread in flight), computes both per-map d values and
// atomicAdds |d_gt - d_pred|/(J*B) straight into the output.
//  - finalize kernel + d[] workspace round-trip eliminated (one launch).
//  - grid 1088 at 4 blocks/CU = 1024 co-resident: ~1.06 residency waves
//    (vs 2.125 ragged waves before), 2x per-block work amortizes ramp.
//  - R9 established phase-2 reloads hit L2/L3, not HBM, so no LDS staging.
__global__ __launch_bounds__(NTH, 8) void hm_pair(const float* __restrict__ outp,
                                                  const float* __restrict__ tgtp,
                                                  float* __restrict__ out)
{
    __shared__ unsigned long long rkP[NWAVE], rkG[NWAVE];
    __shared__ float rsP[NWAVE], rcP[NWAVE], rsG[NWAVE], rcG[NWAVE];

    const int m = blockIdx.x;                      // [0, BJ)
    const int t = threadIdx.x;
    const float4* __restrict__ p4 = (const float4*)(outp + (size_t)m * HW);
    const float4* __restrict__ g4 = (const float4*)(tgtp + (size_t)m * HW);

    // ---- burst both maps (16 float4 outstanding per thread)
    float4 vP[F4PT], vG[F4PT];
#pragma unroll
    for (int k = 0; k < F4PT; ++k) vP[k] = p4[t + k * NTH];
#pragma unroll
    for (int k = 0; k < F4PT; ++k) vG[k] = g4[t + k * NTH];

    // ---- max/argmax for both maps, one barrier
    const unsigned long long keyP = max_key(vP, t);
    const unsigned long long keyG = max_key(vG, t);
    const int wave = t >> 6, lane = t & 63;
    if (lane == 0) { rkP[wave] = keyP; rkG[wave] = keyG; }
    __syncthreads();
    unsigned long long bkP = rkP[0], bkG = rkG[0];
#pragma unroll
    for (int w = 1; w < NWAVE; ++w) {
        bkP = (rkP[w] > bkP) ? rkP[w] : bkP;
        bkG = (rkG[w] > bkG) ? rkG[w] : bkG;
    }

    const float maxvP = __uint_as_float(ford_inv((unsigned int)(bkP >> 32)));
    const int   midxP = (int)~(unsigned int)(bkP & 0xffffffffu);
    const float maxvG = __uint_as_float(ford_inv((unsigned int)(bkG >> 32)));
    const int   midxG = (int)~(unsigned int)(bkG & 0xffffffffu);

    // ---- masked distance sums (reloads hit L2/L3; FETCH proves no HBM re-read)
    float sP = 0.0f, cP = 0.0f, sG = 0.0f, cG = 0.0f;
    masked_sum(vP, t, maxvP * 0.5f, (float)(midxP >> 7), (float)(midxP & 127), sP, cP);
    masked_sum(vG, t, maxvG * 0.5f, (float)(midxG >> 7), (float)(midxG & 127), sG, cG);

#pragma unroll
    for (int off = 32; off >= 1; off >>= 1) {
        sP += __shfl_xor(sP, off, 64);
        cP += __shfl_xor(cP, off, 64);
        sG += __shfl_xor(sG, off, 64);
        cG += __shfl_xor(cG, off, 64);
    }
    if (lane == 0) { rsP[wave] = sP; rcP[wave] = cP; rsG[wave] = sG; rcG[wave] = cG; }
    __syncthreads();
    if (t == 0) {
#pragma unroll
        for (int w = 1; w < NWAVE; ++w) {
            sP += rsP[w]; cP += rcP[w]; sG += rsG[w]; cG += rcG[w];
        }
        const float meanP = sP / fmaxf(cP, 1.0f);
        const float ddP0  = (cP > 0.0f) ? (meanP / 181.02f) : 1.0f;   // MAX_DIST
        const float dP    = (maxvP > 0.0f) ? ddP0 : 0.0f;
        const float meanG = sG / fmaxf(cG, 1.0f);
        const float ddG0  = (cG > 0.0f) ? (meanG / 181.02f) : 1.0f;
        const float dG    = (maxvG > 0.0f) ? ddG0 : 0.0f;
        atomicAdd(out, fabsf(dG - dP) * (1.0f / (17.0f * 64.0f)));
    }
}

extern "C" void kernel_launch(void* const* d_in, const int* in_sizes, int n_in,
                              void* d_out, int out_size, void* d_ws, size_t ws_size,
                              hipStream_t stream) {
    const float* outp = (const float*)d_in[0];     // [64,17,128,128] f32
    const float* tgtp = (const float*)d_in[1];

    hipMemsetAsync(d_out, 0, sizeof(float), stream);
    hm_pair<<<dim3(BJ), dim3(NTH), 0, stream>>>(outp, tgtp, (float*)d_out);
}